// Round 17
// baseline (259.162 us; speedup 1.0000x reference)
//
#include <hip/hip_runtime.h>

// CompressedLinear: out = x[8192,4096] @ (W_int8[4096,4096]*scale)^T + bias.
// Round 17: single-variable shape test on the R16 skeleton (140.2us, 4
// waves/SIMD). ONLY change: mfma_i32_32x32x32_i8 -> mfma_i32_16x16x64_i8
// (4x4 16-blocks per 64x64 wave tile, 32 MFMA/wave/K-tile of ~1/4 length).
// Rationale: m201 (bf16, 16x16 frags, same port:MFMA demand ratio) hits 62%
// MfmaUtil; every 32x32 i8 variant (R7-R16, 11 schedules) lands at 44-45%.
// Shape granularity is the last untested structural difference.
// Staging/swizzle image/ledger/barriers: verbatim R16. Read swizzle re-derived
// for 16-row blocks: nibble = (lane&7)^((lane>>3)&1)^(2*(mt&1)) — 8 lanes per
// bank-quad = 2/bank (same pattern as current, measured 0 conflicts).
// Int32 accum exact -> absmax must stay exactly 2.265625.

#define BM 256
#define BN 256
#define BKB 128                 // K-bytes per tile = 128 int8

constexpr int Mdim = 8192;
constexpr int Ndim = 4096;
constexpr int Kdim = 4096;
constexpr int KT = Kdim / BKB;  // 32

typedef __attribute__((ext_vector_type(4)))  int   int32x4;
typedef __attribute__((ext_vector_type(8)))  short short8;
typedef __attribute__((ext_vector_type(4)))  float f32x4;
typedef unsigned short ushort_t;

__device__ __forceinline__ unsigned short f2bf(float f) {
    union { float f; unsigned u; } v; v.f = f;
    unsigned r = v.u + 0x7FFFu + ((v.u >> 16) & 1u);
    return (unsigned short)(r >> 16);
}

__device__ __forceinline__ void gload_lds16(const void* g, void* l) {
    __builtin_amdgcn_global_load_lds(
        (const __attribute__((address_space(1))) void*)g,
        (__attribute__((address_space(3))) void*)l, 16, 0, 0);
}

#define BARRIER() __builtin_amdgcn_s_barrier()
#define WAITV0()  asm volatile("s_waitcnt vmcnt(0)" ::: "memory")

// ---------------- prep kernels ----------------------------------------------

__global__ __launch_bounds__(256)
void quant_x_rowwise(const float* __restrict__ x, char* __restrict__ xq,
                     float* __restrict__ sx) {
    const int row = blockIdx.x;
    const float4* xr = reinterpret_cast<const float4*>(x + (size_t)row * Kdim);
    const int tid = threadIdx.x;
    float4 v[4];
    float am = 0.f;
    #pragma unroll
    for (int j = 0; j < 4; ++j) {
        v[j] = xr[tid + 256 * j];
        am = fmaxf(am, fmaxf(fmaxf(fabsf(v[j].x), fabsf(v[j].y)),
                             fmaxf(fabsf(v[j].z), fabsf(v[j].w))));
    }
    #pragma unroll
    for (int off = 32; off; off >>= 1)
        am = fmaxf(am, __shfl_xor(am, off, 64));
    __shared__ float red[4];
    if ((tid & 63) == 0) red[tid >> 6] = am;
    __syncthreads();
    am = fmaxf(fmaxf(red[0], red[1]), fmaxf(red[2], red[3]));
    am = fmaxf(am, 1e-30f);
    if (tid == 0) sx[row] = am / 127.f;
    const float inv = 127.f / am;
    int* outw = reinterpret_cast<int*>(xq + (size_t)row * Kdim);
    #pragma unroll
    for (int j = 0; j < 4; ++j) {
        const int q0 = (int)rintf(v[j].x * inv) & 255;
        const int q1 = (int)rintf(v[j].y * inv) & 255;
        const int q2 = (int)rintf(v[j].z * inv) & 255;
        const int q3 = (int)rintf(v[j].w * inv) & 255;
        outw[tid + 256 * j] = q0 | (q1 << 8) | (q2 << 16) | (q3 << 24);
    }
}

__global__ __launch_bounds__(256)
void pack_w_int8(const int* __restrict__ w, char* __restrict__ wq, int n4) {
    int idx = blockIdx.x * blockDim.x + threadIdx.x;
    const int stride = gridDim.x * blockDim.x;
    int* out = reinterpret_cast<int*>(wq);
    for (int i = idx; i < n4; i += stride) {
        const int4 a = reinterpret_cast<const int4*>(w)[i];
        out[i] = (a.x & 255) | ((a.y & 255) << 8) |
                 ((a.z & 255) << 16) | ((a.w & 255) << 24);
    }
}

// ---------------- 256x256 16-wave int8 GEMM (16x16x64 frags) ----------------

__global__ __launch_bounds__(1024)
void gemm_i8_16x16(const char* __restrict__ A,   // [M][K] int8
                   const char* __restrict__ B,   // [N][K] int8
                   const float* __restrict__ scale,
                   const float* __restrict__ bias,
                   const float* __restrict__ sx,
                   float* __restrict__ Out)
{
    // [buf][region: A rows0-127, A rows128-255, B0, B1][16 KiB] = 128 KiB
    __shared__ __align__(16) char smem[2][4][16384];

    const int tid = threadIdx.x;
    int bid = blockIdx.x;
    bid = (bid & 7) * 64 + (bid >> 3);          // bijective XCD swizzle (512%8==0)
    const int tn = bid & 15;                    // N/BN = 16
    const int tm = bid >> 4;                    // M/BM = 32
    const int brow = tm * BM;
    const int bcol = tn * BN;

    const int lane = tid & 63;
    const int w    = tid >> 6;                  // 16 waves
    const int wr   = w >> 2;                    // 4 M-waves
    const int wc   = w & 3;                     // 4 N-waves
    const int l15  = lane & 15;
    const int lg   = lane >> 4;                 // 0..3: k-chunk selector
    const size_t K1 = (size_t)Kdim;

    // ---- staging: verbatim R16 (two-level swizzle image, zero-conflict) ----
    const int swzb = ((lane & 7) ^ (lane >> 3) ^ (w & 3)) << 4;
    const char* aStageSrc = A + (size_t)(brow + w * 8 + (lane >> 3)) * K1 + swzb;
    const char* bStageSrc = B + (size_t)(bcol + w * 8 + (lane >> 3)) * K1 + swzb;

    auto stageTile = [&](int b, int tt) {       // 4 gloads/wave (1 KiB each)
        const size_t ko = (size_t)tt * BKB;
        #pragma unroll
        for (int hh = 0; hh < 2; ++hh)
            gload_lds16(aStageSrc + (size_t)(hh * 128) * K1 + ko,
                        &smem[b][hh][w * 1024]);
        #pragma unroll
        for (int hh = 0; hh < 2; ++hh)
            gload_lds16(bStageSrc + (size_t)(hh * 128) * K1 + ko,
                        &smem[b][2 + hh][w * 1024]);
    };

    // ---- read addressing (16-row blocks) ----
    // Wave owns A rows [wr*64, +64), B rows [wc*64, +64). For block mt:
    // LDS row = (wr&1)*64 + mt*16 + l15. Image involution: LDS[r][slot] =
    // global[r][slot ^ nib(r)*16], nib(r) = (r&7)^((r>>3)&3)
    //   = (lane&7) ^ (2*(mt&1)) ^ ((lane>>3)&1)   [only mt parity matters]
    const char* aBaseL[2] = {
        &smem[0][wr >> 1][0] + (((wr & 1) * 64) + l15) * 128,
        &smem[1][wr >> 1][0] + (((wr & 1) * 64) + l15) * 128 };
    const char* bBaseL[2] = {
        &smem[0][2 + (wc >> 1)][0] + (((wc & 1) * 64) + l15) * 128,
        &smem[1][2 + (wc >> 1)][0] + (((wc & 1) * 64) + l15) * 128 };

    const int nib0 = (lane & 7) ^ ((lane >> 3) & 1);
    int colb[2][2];   // [block parity][kk]
    #pragma unroll
    for (int par = 0; par < 2; ++par)
        #pragma unroll
        for (int kk = 0; kk < 2; ++kk)
            colb[par][kk] = (kk * 64 + lg * 16) ^ ((nib0 ^ (2 * par)) << 4);

    int32x4 acc[4][4] = {};      // [mt][nt] 16x16 tiles — 64 regs
    int32x4 af[4], bf[4];        // current kk fragments — 32 regs

    // ---- prologue: stage t0 -> buf0, drain, publish
    stageTile(0, 0);
    WAITV0();
    BARRIER();

    // ---- main loop: tiles 0..30 stage t+1; one WAITV0+BARRIER per tile ----
    for (int t = 0; t < KT - 1; ++t) {
        const int c = t & 1;
        stageTile(1 - c, t + 1);   // lands under this tile's reads+MFMA

        #pragma unroll
        for (int kk = 0; kk < 2; ++kk) {
            #pragma unroll
            for (int mt = 0; mt < 4; ++mt)
                af[mt] = *reinterpret_cast<const int32x4*>(
                    aBaseL[c] + mt * 2048 + colb[mt & 1][kk]);
            #pragma unroll
            for (int nt = 0; nt < 4; ++nt)
                bf[nt] = *reinterpret_cast<const int32x4*>(
                    bBaseL[c] + nt * 2048 + colb[nt & 1][kk]);
            __builtin_amdgcn_s_setprio(1);
            #pragma unroll
            for (int mt = 0; mt < 4; ++mt)
                #pragma unroll
                for (int nt = 0; nt < 4; ++nt)
                    acc[mt][nt] = __builtin_amdgcn_mfma_i32_16x16x64_i8(
                        af[mt], bf[nt], acc[mt][nt], 0, 0, 0);
            __builtin_amdgcn_s_setprio(0);
        }
        WAITV0();      // stage issued ~1 tile ago: mostly covered
        BARRIER();     // publish buf(1-c)
    }
    // ---- tile 31 (buf1): no stage, no sync
    {
        #pragma unroll
        for (int kk = 0; kk < 2; ++kk) {
            #pragma unroll
            for (int mt = 0; mt < 4; ++mt)
                af[mt] = *reinterpret_cast<const int32x4*>(
                    aBaseL[1] + mt * 2048 + colb[mt & 1][kk]);
            #pragma unroll
            for (int nt = 0; nt < 4; ++nt)
                bf[nt] = *reinterpret_cast<const int32x4*>(
                    bBaseL[1] + nt * 2048 + colb[nt & 1][kk]);
            __builtin_amdgcn_s_setprio(1);
            #pragma unroll
            for (int mt = 0; mt < 4; ++mt)
                #pragma unroll
                for (int nt = 0; nt < 4; ++nt)
                    acc[mt][nt] = __builtin_amdgcn_mfma_i32_16x16x64_i8(
                        af[mt], bf[nt], acc[mt][nt], 0, 0, 0);
            __builtin_amdgcn_s_setprio(0);
        }
    }

    // epilogue: out = acc * scale[col] * scale_x[row] + bias[col]
    // C/D (16x16): col = lane&15, row = (lane>>4)*4 + reg  [m89/m91 verified]
    #pragma unroll
    for (int mt = 0; mt < 4; ++mt) {
        const int rb = brow + wr * 64 + mt * 16 + lg * 4;
        float sxr[4];
        #pragma unroll
        for (int r = 0; r < 4; ++r) sxr[r] = sx[rb + r];
        #pragma unroll
        for (int nt = 0; nt < 4; ++nt) {
            const int col = bcol + wc * 64 + nt * 16 + l15;
            const float sc = scale[col];
            const float bi = bias[col];
            #pragma unroll
            for (int r = 0; r < 4; ++r) {
                Out[(size_t)(rb + r) * Ndim + col] =
                    (float)acc[mt][nt][r] * (sc * sxr[r]) + bi;
            }
        }
    }
}

// ---------------- fallback (round-1 kernel) if ws too small -----------------

__device__ __forceinline__ int swz_fb(int row, int colbyte) {
    return row * 128 + (colbyte ^ ((row & 7) << 4));
}

__global__ __launch_bounds__(256)
void compressed_linear_fb(const float* __restrict__ X,
                          const int*   __restrict__ W,
                          const float* __restrict__ scale,
                          const float* __restrict__ bias,
                          float* __restrict__ Out)
{
    __shared__ __align__(16) ushort_t lA[128 * 64];
    __shared__ __align__(16) ushort_t lB[128 * 64];
    const int tid = threadIdx.x;
    const int bid = blockIdx.x;
    const int tn = bid & 31, tm = bid >> 5;
    const int brow = tm * 128, bcol = tn * 128;
    const int r0 = tid >> 3, c0 = tid & 7;
    float4 aPre[4][2]; int4 bPre[4][2];
    const int lane = tid & 63, w = tid >> 6;
    const int wr = w >> 1, wc = w & 1, fr = lane & 15, fq = lane >> 4;
    f32x4 acc[4][4] = {};

    auto loadTiles = [&](int t) {
        const int k0 = t * 64;
        #pragma unroll
        for (int i = 0; i < 4; i++) {
            const int row = r0 + 32 * i;
            const float4* pa = reinterpret_cast<const float4*>(X + (size_t)(brow + row) * Kdim + k0 + c0 * 8);
            aPre[i][0] = pa[0]; aPre[i][1] = pa[1];
            const int4* pb = reinterpret_cast<const int4*>(W + (size_t)(bcol + row) * Kdim + k0 + c0 * 8);
            bPre[i][0] = pb[0]; bPre[i][1] = pb[1];
        }
    };
    auto writeLDS = [&]() {
        #pragma unroll
        for (int i = 0; i < 4; i++) {
            const int row = r0 + 32 * i;
            const int off = swz_fb(row, c0 * 16);
            short8 va, vb;
            va[0] = (short)f2bf(aPre[i][0].x); va[1] = (short)f2bf(aPre[i][0].y);
            va[2] = (short)f2bf(aPre[i][0].z); va[3] = (short)f2bf(aPre[i][0].w);
            va[4] = (short)f2bf(aPre[i][1].x); va[5] = (short)f2bf(aPre[i][1].y);
            va[6] = (short)f2bf(aPre[i][1].z); va[7] = (short)f2bf(aPre[i][1].w);
            vb[0] = (short)f2bf((float)bPre[i][0].x); vb[1] = (short)f2bf((float)bPre[i][0].y);
            vb[2] = (short)f2bf((float)bPre[i][0].z); vb[3] = (short)f2bf((float)bPre[i][0].w);
            vb[4] = (short)f2bf((float)bPre[i][1].x); vb[5] = (short)f2bf((float)bPre[i][1].y);
            vb[6] = (short)f2bf((float)bPre[i][1].z); vb[7] = (short)f2bf((float)bPre[i][1].w);
            *reinterpret_cast<short8*>(reinterpret_cast<char*>(lA) + off) = va;
            *reinterpret_cast<short8*>(reinterpret_cast<char*>(lB) + off) = vb;
        }
    };

    loadTiles(0);
    for (int t = 0; t < Kdim / 64; t++) {
        writeLDS();
        __syncthreads();
        if (t + 1 < Kdim / 64) loadTiles(t + 1);
        #pragma unroll
        for (int kk = 0; kk < 2; kk++) {
            short8 afv[4], bfv[4];
            const int cb = kk * 64 + fq * 16;
            #pragma unroll
            for (int m = 0; m < 4; m++) {
                const int row = wr * 64 + m * 16 + fr;
                afv[m] = *reinterpret_cast<const short8*>(reinterpret_cast<const char*>(lA) + swz_fb(row, cb));
            }
            #pragma unroll
            for (int n = 0; n < 4; n++) {
                const int row = wc * 64 + n * 16 + fr;
                bfv[n] = *reinterpret_cast<const short8*>(reinterpret_cast<const char*>(lB) + swz_fb(row, cb));
            }
            #pragma unroll
            for (int m = 0; m < 4; m++)
                #pragma unroll
                for (int n = 0; n < 4; n++)
                    acc[m][n] = __builtin_amdgcn_mfma_f32_16x16x32_bf16(afv[m], bfv[n], acc[m][n], 0, 0, 0);
        }
        __syncthreads();
    }
    #pragma unroll
    for (int n = 0; n < 4; n++) {
        const int col = bcol + wc * 64 + n * 16 + fr;
        const float sc = scale[col];
        const float bi = bias[col];
        #pragma unroll
        for (int m = 0; m < 4; m++) {
            const int rbase = brow + wr * 64 + m * 16 + fq * 4;
            #pragma unroll
            for (int j = 0; j < 4; j++)
                Out[(size_t)(rbase + j) * Ndim + col] = acc[m][n][j] * sc + bi;
        }
    }
}

// ---------------------------------------------------------------------------

extern "C" void kernel_launch(void* const* d_in, const int* in_sizes, int n_in,
                              void* d_out, int out_size, void* d_ws, size_t ws_size,
                              hipStream_t stream) {
    const float* x     = (const float*)d_in[0];
    const int*   w8    = (const int*)d_in[1];
    const float* scale = (const float*)d_in[2];
    const float* bias  = (const float*)d_in[3];
    float* out = (float*)d_out;

    const size_t xq_bytes = (size_t)Mdim * Kdim;        // 32 MiB
    const size_t wq_bytes = (size_t)Ndim * Kdim;        // 16 MiB
    const size_t sx_bytes = (size_t)Mdim * sizeof(float);

    if (ws_size >= xq_bytes + wq_bytes + sx_bytes) {
        char*  xq = (char*)d_ws;
        char*  wq = (char*)d_ws + xq_bytes;
        float* sx = (float*)((char*)d_ws + xq_bytes + wq_bytes);
        quant_x_rowwise<<<Mdim, 256, 0, stream>>>(x, xq, sx);
        pack_w_int8<<<2048, 256, 0, stream>>>(w8, wq, (Ndim * Kdim) / 4);
        dim3 grid((Mdim / BM) * (Ndim / BN));           // 512 blocks
        gemm_i8_16x16<<<grid, dim3(1024), 0, stream>>>(xq, wq, scale, bias, sx, out);
    } else {
        dim3 grid((Mdim / 128) * (Ndim / 128));
        compressed_linear_fb<<<grid, dim3(256), 0, stream>>>(x, w8, scale, bias, out);
    }
}

// Round 18
// 188.530 us; speedup vs baseline: 1.3746x; 1.3746x over previous
//
#include <hip/hip_runtime.h>

// CompressedLinear: out = x[8192,4096] @ (W_int8[4096,4096]*scale)^T + bias.
// FINAL (restore of round-16 champion, 188.2us e2e / 140.2us GEMM):
//   - x quantized per-row to int8 (exact-int32 accumulation; absmax 2.2656
//     << 4.54 threshold), W packed int32->int8 (exact).
//   - 256x256 tile / 512 blocks (L2/L3 locality: FETCH ~148MB), 16 waves of
//     64x64 (acc 64 regs -> ~128 total -> 16 waves/CU), BKB=128.
//   - global_load_lds(16B) staging with two-level XOR swizzle (zero bank
//     conflicts, verified), one counted-drain WAITV0+barrier per K-tile,
//     mfma_i32_32x32x32_i8 ks-outer (acc revisit distance 4), setprio(1),
//     bijective XCD block swizzle.
// Plateau evidence: 12 schedule/shape/occupancy variants (R7-R17) all land
// 140-150us GEMM; LDS-port + MFMA + sync sum (~5272 cyc/K-tile measured).

#define BM 256
#define BN 256
#define BKB 128                 // K-bytes per tile = 128 int8

constexpr int Mdim = 8192;
constexpr int Ndim = 4096;
constexpr int Kdim = 4096;
constexpr int KT = Kdim / BKB;  // 32

typedef __attribute__((ext_vector_type(4)))  int   int32x4;
typedef __attribute__((ext_vector_type(16))) int   int32x16;
typedef __attribute__((ext_vector_type(8)))  short short8;
typedef __attribute__((ext_vector_type(4)))  float f32x4;
typedef unsigned short ushort_t;

__device__ __forceinline__ unsigned short f2bf(float f) {
    union { float f; unsigned u; } v; v.f = f;
    unsigned r = v.u + 0x7FFFu + ((v.u >> 16) & 1u);
    return (unsigned short)(r >> 16);
}

__device__ __forceinline__ void gload_lds16(const void* g, void* l) {
    __builtin_amdgcn_global_load_lds(
        (const __attribute__((address_space(1))) void*)g,
        (__attribute__((address_space(3))) void*)l, 16, 0, 0);
}

#define BARRIER() __builtin_amdgcn_s_barrier()
#define WAITV0()  asm volatile("s_waitcnt vmcnt(0)" ::: "memory")

// ---------------- prep kernels ----------------------------------------------

__global__ __launch_bounds__(256)
void quant_x_rowwise(const float* __restrict__ x, char* __restrict__ xq,
                     float* __restrict__ sx) {
    const int row = blockIdx.x;
    const float4* xr = reinterpret_cast<const float4*>(x + (size_t)row * Kdim);
    const int tid = threadIdx.x;
    float4 v[4];
    float am = 0.f;
    #pragma unroll
    for (int j = 0; j < 4; ++j) {
        v[j] = xr[tid + 256 * j];
        am = fmaxf(am, fmaxf(fmaxf(fabsf(v[j].x), fabsf(v[j].y)),
                             fmaxf(fabsf(v[j].z), fabsf(v[j].w))));
    }
    #pragma unroll
    for (int off = 32; off; off >>= 1)
        am = fmaxf(am, __shfl_xor(am, off, 64));
    __shared__ float red[4];
    if ((tid & 63) == 0) red[tid >> 6] = am;
    __syncthreads();
    am = fmaxf(fmaxf(red[0], red[1]), fmaxf(red[2], red[3]));
    am = fmaxf(am, 1e-30f);
    if (tid == 0) sx[row] = am / 127.f;
    const float inv = 127.f / am;
    int* outw = reinterpret_cast<int*>(xq + (size_t)row * Kdim);
    #pragma unroll
    for (int j = 0; j < 4; ++j) {
        const int q0 = (int)rintf(v[j].x * inv) & 255;
        const int q1 = (int)rintf(v[j].y * inv) & 255;
        const int q2 = (int)rintf(v[j].z * inv) & 255;
        const int q3 = (int)rintf(v[j].w * inv) & 255;
        outw[tid + 256 * j] = q0 | (q1 << 8) | (q2 << 16) | (q3 << 24);
    }
}

__global__ __launch_bounds__(256)
void pack_w_int8(const int* __restrict__ w, char* __restrict__ wq, int n4) {
    int idx = blockIdx.x * blockDim.x + threadIdx.x;
    const int stride = gridDim.x * blockDim.x;
    int* out = reinterpret_cast<int*>(wq);
    for (int i = idx; i < n4; i += stride) {
        const int4 a = reinterpret_cast<const int4*>(w)[i];
        out[i] = (a.x & 255) | ((a.y & 255) << 8) |
                 ((a.z & 255) << 16) | ((a.w & 255) << 24);
    }
}

// ---------------- 256x256 16-wave int8 GEMM ---------------------------------

__global__ __launch_bounds__(1024)
void gemm_i8_16w(const char* __restrict__ A,   // [M][K] int8
                 const char* __restrict__ B,   // [N][K] int8
                 const float* __restrict__ scale,
                 const float* __restrict__ bias,
                 const float* __restrict__ sx,
                 float* __restrict__ Out)
{
    // [buf][region: A rows0-127, A rows128-255, B0, B1][16 KiB] = 128 KiB
    __shared__ __align__(16) char smem[2][4][16384];

    const int tid = threadIdx.x;
    int bid = blockIdx.x;
    bid = (bid & 7) * 64 + (bid >> 3);          // bijective XCD swizzle (512%8==0)
    const int tn = bid & 15;                    // N/BN = 16
    const int tm = bid >> 4;                    // M/BM = 32
    const int brow = tm * BM;
    const int bcol = tn * BN;

    const int lane = tid & 63;
    const int w    = tid >> 6;                  // 16 waves
    const int wr   = w >> 2;                    // 4 M-waves
    const int wc   = w & 3;                     // 4 N-waves
    const int r32  = lane & 31;
    const int h    = lane >> 5;
    const size_t K1 = (size_t)Kdim;

    // staging (two-level swizzle; invariants: row = hh*128 + w*8 + (lane>>3)
    // gives row&7 = lane>>3 and (row>>3)&3 = w&3 for all hh)
    const int swzb = ((lane & 7) ^ (lane >> 3) ^ (w & 3)) << 4;
    const char* aStageSrc = A + (size_t)(brow + w * 8 + (lane >> 3)) * K1 + swzb;
    const char* bStageSrc = B + (size_t)(bcol + w * 8 + (lane >> 3)) * K1 + swzb;

    // stage the FULL tile tt into buf b: 4 gloads/wave (1 KiB each)
    auto stageTile = [&](int b, int tt) {
        const size_t ko = (size_t)tt * BKB;
        #pragma unroll
        for (int hh = 0; hh < 2; ++hh)
            gload_lds16(aStageSrc + (size_t)(hh * 128) * K1 + ko,
                        &smem[b][hh][w * 1024]);
        #pragma unroll
        for (int hh = 0; hh < 2; ++hh)
            gload_lds16(bStageSrc + (size_t)(hh * 128) * K1 + ko,
                        &smem[b][2 + hh][w * 1024]);
    };

    // ds_read bases: wave owns A rows [wr*64, wr*64+64), B rows [wc*64, ...)
    const char* aBase[2] = {
        &smem[0][wr >> 1][0] + (((wr & 1) * 64) + r32) * 128,
        &smem[1][wr >> 1][0] + (((wr & 1) * 64) + r32) * 128 };
    const char* bBase[2] = {
        &smem[0][2 + (wc >> 1)][0] + (((wc & 1) * 64) + r32) * 128,
        &smem[1][2 + (wc >> 1)][0] + (((wc & 1) * 64) + r32) * 128 };
    const int frx = ((r32 & 7) ^ (r32 >> 3)) << 4;
    int colb[4];
    #pragma unroll
    for (int ks = 0; ks < 4; ++ks) colb[ks] = (ks * 32 + h * 16) ^ frx;

    int32x16 acc[2][2] = {};     // [mt][nt] — 64 regs
    int32x4 af[2][2], bf[2][2];  // [mt|nt][kf] — reused across ks-pairs

    auto ldA = [&](int buf, int ksp) {
        #pragma unroll
        for (int mt = 0; mt < 2; ++mt)
            #pragma unroll
            for (int kf = 0; kf < 2; ++kf)
                af[mt][kf] = *reinterpret_cast<const int32x4*>(
                    aBase[buf] + mt * 4096 + colb[ksp * 2 + kf]);
    };
    auto ldB = [&](int buf, int ksp) {
        #pragma unroll
        for (int nt = 0; nt < 2; ++nt)
            #pragma unroll
            for (int kf = 0; kf < 2; ++kf)
                bf[nt][kf] = *reinterpret_cast<const int32x4*>(
                    bBase[buf] + nt * 4096 + colb[ksp * 2 + kf]);
    };

    // half-tile MFMA: 2kf x 2mt x 2nt = 8 MFMA, acc revisit distance 4
    auto MFMAH = [&]() {
        __builtin_amdgcn_s_setprio(1);
        #pragma unroll
        for (int kf = 0; kf < 2; ++kf)
            #pragma unroll
            for (int mt = 0; mt < 2; ++mt)
                #pragma unroll
                for (int nt = 0; nt < 2; ++nt)
                    acc[mt][nt] = __builtin_amdgcn_mfma_i32_32x32x32_i8(
                        af[mt][kf], bf[nt][kf], acc[mt][nt], 0, 0, 0);
        __builtin_amdgcn_s_setprio(0);
    };

    // ---- prologue: stage t0 -> buf0, drain, publish
    stageTile(0, 0);
    WAITV0();
    BARRIER();

    // ---- main loop: tiles 0..30 stage t+1; one WAITV0+BARRIER per tile ----
    for (int t = 0; t < KT - 1; ++t) {
        const int c = t & 1;
        // issue next-tile stage early (lands under this tile's reads+MFMA)
        stageTile(1 - c, t + 1);
        // half 1 (ks 0-1)
        ldA(c, 0); ldB(c, 0);
        MFMAH();
        // half 2 (ks 2-3)
        ldA(c, 1); ldB(c, 1);
        MFMAH();
        WAITV0();      // stage issued ~700 cyc ago: mostly covered
        BARRIER();     // publish buf(1-c) for tile t+1
    }
    // ---- tile 31 (buf1): no stage, no sync
    {
        ldA(1, 0); ldB(1, 0);
        MFMAH();
        ldA(1, 1); ldB(1, 1);
        MFMAH();
    }

    // epilogue: out = acc * scale[col] * scale_x[row] + bias[col]
    // C/D (32x32): col=lane&31, row=(reg&3)+8*(reg>>2)+4*(lane>>5)
    #pragma unroll
    for (int mt = 0; mt < 2; ++mt) {
        const int rb = brow + wr * 64 + mt * 32 + 4 * h;
        float sxr[4][4];
        #pragma unroll
        for (int q = 0; q < 4; ++q)
            #pragma unroll
            for (int r = 0; r < 4; ++r)
                sxr[q][r] = sx[rb + 8 * q + r];
        #pragma unroll
        for (int nt = 0; nt < 2; ++nt) {
            const int col = bcol + wc * 64 + nt * 32 + r32;
            const float sc = scale[col];
            const float bi = bias[col];
            #pragma unroll
            for (int q = 0; q < 4; ++q) {
                const int r4 = rb + 8 * q;
                #pragma unroll
                for (int r = 0; r < 4; ++r) {
                    Out[(size_t)(r4 + r) * Ndim + col] =
                        (float)acc[mt][nt][q * 4 + r] * (sc * sxr[q][r]) + bi;
                }
            }
        }
    }
}

// ---------------- fallback (round-1 kernel) if ws too small -----------------

__device__ __forceinline__ int swz_fb(int row, int colbyte) {
    return row * 128 + (colbyte ^ ((row & 7) << 4));
}

__global__ __launch_bounds__(256)
void compressed_linear_fb(const float* __restrict__ X,
                          const int*   __restrict__ W,
                          const float* __restrict__ scale,
                          const float* __restrict__ bias,
                          float* __restrict__ Out)
{
    __shared__ __align__(16) ushort_t lA[128 * 64];
    __shared__ __align__(16) ushort_t lB[128 * 64];
    const int tid = threadIdx.x;
    const int bid = blockIdx.x;
    const int tn = bid & 31, tm = bid >> 5;
    const int brow = tm * 128, bcol = tn * 128;
    const int r0 = tid >> 3, c0 = tid & 7;
    float4 aPre[4][2]; int4 bPre[4][2];
    const int lane = tid & 63, w = tid >> 6;
    const int wr = w >> 1, wc = w & 1, fr = lane & 15, fq = lane >> 4;
    f32x4 acc[4][4] = {};

    auto loadTiles = [&](int t) {
        const int k0 = t * 64;
        #pragma unroll
        for (int i = 0; i < 4; i++) {
            const int row = r0 + 32 * i;
            const float4* pa = reinterpret_cast<const float4*>(X + (size_t)(brow + row) * Kdim + k0 + c0 * 8);
            aPre[i][0] = pa[0]; aPre[i][1] = pa[1];
            const int4* pb = reinterpret_cast<const int4*>(W + (size_t)(bcol + row) * Kdim + k0 + c0 * 8);
            bPre[i][0] = pb[0]; bPre[i][1] = pb[1];
        }
    };
    auto writeLDS = [&]() {
        #pragma unroll
        for (int i = 0; i < 4; i++) {
            const int row = r0 + 32 * i;
            const int off = swz_fb(row, c0 * 16);
            short8 va, vb;
            va[0] = (short)f2bf(aPre[i][0].x); va[1] = (short)f2bf(aPre[i][0].y);
            va[2] = (short)f2bf(aPre[i][0].z); va[3] = (short)f2bf(aPre[i][0].w);
            va[4] = (short)f2bf(aPre[i][1].x); va[5] = (short)f2bf(aPre[i][1].y);
            va[6] = (short)f2bf(aPre[i][1].z); va[7] = (short)f2bf(aPre[i][1].w);
            vb[0] = (short)f2bf((float)bPre[i][0].x); vb[1] = (short)f2bf((float)bPre[i][0].y);
            vb[2] = (short)f2bf((float)bPre[i][0].z); vb[3] = (short)f2bf((float)bPre[i][0].w);
            vb[4] = (short)f2bf((float)bPre[i][1].x); vb[5] = (short)f2bf((float)bPre[i][1].y);
            vb[6] = (short)f2bf((float)bPre[i][1].z); vb[7] = (short)f2bf((float)bPre[i][1].w);
            *reinterpret_cast<short8*>(reinterpret_cast<char*>(lA) + off) = va;
            *reinterpret_cast<short8*>(reinterpret_cast<char*>(lB) + off) = vb;
        }
    };

    loadTiles(0);
    for (int t = 0; t < Kdim / 64; t++) {
        writeLDS();
        __syncthreads();
        if (t + 1 < Kdim / 64) loadTiles(t + 1);
        #pragma unroll
        for (int kk = 0; kk < 2; kk++) {
            short8 afv[4], bfv[4];
            const int cb = kk * 64 + fq * 16;
            #pragma unroll
            for (int m = 0; m < 4; m++) {
                const int row = wr * 64 + m * 16 + fr;
                afv[m] = *reinterpret_cast<const short8*>(reinterpret_cast<const char*>(lA) + swz_fb(row, cb));
            }
            #pragma unroll
            for (int n = 0; n < 4; n++) {
                const int row = wc * 64 + n * 16 + fr;
                bfv[n] = *reinterpret_cast<const short8*>(reinterpret_cast<const char*>(lB) + swz_fb(row, cb));
            }
            #pragma unroll
            for (int m = 0; m < 4; m++)
                #pragma unroll
                for (int n = 0; n < 4; n++)
                    acc[m][n] = __builtin_amdgcn_mfma_f32_16x16x32_bf16(afv[m], bfv[n], acc[m][n], 0, 0, 0);
        }
        __syncthreads();
    }
    #pragma unroll
    for (int n = 0; n < 4; n++) {
        const int col = bcol + wc * 64 + n * 16 + fr;
        const float sc = scale[col];
        const float bi = bias[col];
        #pragma unroll
        for (int m = 0; m < 4; m++) {
            const int rbase = brow + wr * 64 + m * 16 + fq * 4;
            #pragma unroll
            for (int j = 0; j < 4; j++)
                Out[(size_t)(rbase + j) * Ndim + col] = acc[m][n][j] * sc + bi;
        }
    }
}

// ---------------------------------------------------------------------------

extern "C" void kernel_launch(void* const* d_in, const int* in_sizes, int n_in,
                              void* d_out, int out_size, void* d_ws, size_t ws_size,
                              hipStream_t stream) {
    const float* x     = (const float*)d_in[0];
    const int*   w8    = (const int*)d_in[1];
    const float* scale = (const float*)d_in[2];
    const float* bias  = (const float*)d_in[3];
    float* out = (float*)d_out;

    const size_t xq_bytes = (size_t)Mdim * Kdim;        // 32 MiB
    const size_t wq_bytes = (size_t)Ndim * Kdim;        // 16 MiB
    const size_t sx_bytes = (size_t)Mdim * sizeof(float);

    if (ws_size >= xq_bytes + wq_bytes + sx_bytes) {
        char*  xq = (char*)d_ws;
        char*  wq = (char*)d_ws + xq_bytes;
        float* sx = (float*)((char*)d_ws + xq_bytes + wq_bytes);
        quant_x_rowwise<<<Mdim, 256, 0, stream>>>(x, xq, sx);
        pack_w_int8<<<2048, 256, 0, stream>>>(w8, wq, (Ndim * Kdim) / 4);
        dim3 grid((Mdim / BM) * (Ndim / BN));           // 512 blocks
        gemm_i8_16w<<<grid, dim3(1024), 0, stream>>>(xq, wq, scale, bias, sx, out);
    } else {
        dim3 grid((Mdim / 128) * (Ndim / 128));
        compressed_linear_fb<<<grid, dim3(256), 0, stream>>>(x, w8, scale, bias, out);
    }
}